// Round 6
// baseline (1446.594 us; speedup 1.0000x reference)
//
#include <hip/hip_runtime.h>
#include <hip/hip_bf16.h>
#include <cstdint>
#include <cstddef>

// Problem constants (from reference)
#define NPTS  1000000
#define BSEG  2000
#define DIN   16
#define HDIM  256
#define DOUT  128
#define MT    64                      // points per tile
#define NTILE (NPTS / MT)             // 15625 (exact)
#define NWG   512                     // 2 WGs/CU x 256 CUs
#define TPW   ((NTILE + NWG - 1) / NWG)  // 31 tiles per WG (chunked)

typedef __bf16          bf16x8 __attribute__((ext_vector_type(8)));
typedef unsigned short  us16x8 __attribute__((ext_vector_type(8)));
typedef unsigned int    u32x4  __attribute__((ext_vector_type(4)));
typedef float           f32x4  __attribute__((ext_vector_type(4)));

static __device__ __forceinline__ unsigned short f2bf(float x) {
    unsigned int u = __float_as_uint(x);
    u += 0x7fffu + ((u >> 16) & 1u);
    return (unsigned short)(u >> 16);
}
static __device__ __forceinline__ bf16x8 ldb8(const unsigned short* p) {
    u32x4 v = *(const u32x4*)p;
    return __builtin_bit_cast(bf16x8, v);
}
static __device__ __forceinline__ f32x4 mfma16(bf16x8 a, bf16x8 b, f32x4 c) {
    return __builtin_amdgcn_mfma_f32_16x16x32_bf16(a, b, c, 0, 0, 0);
}
static __device__ __forceinline__ void keep(bf16x8& v) {
    u32x4 u = __builtin_bit_cast(u32x4, v);
    unsigned a0 = u[0], a1 = u[1], a2 = u[2], a3 = u[3];
    asm volatile("" : "+v"(a0), "+v"(a1), "+v"(a2), "+v"(a3));
    u32x4 r; r[0] = a0; r[1] = a1; r[2] = a2; r[3] = a3;
    v = __builtin_bit_cast(bf16x8, r);
}
// async 16B/lane global->LDS (wave-uniform LDS base, lane*16 scatter)
static __device__ __forceinline__ void async16(const float* g, float* l) {
    __builtin_amdgcn_global_load_lds(
        (const __attribute__((address_space(1))) void*)g,
        (__attribute__((address_space(3))) void*)l, 16, 0, 0);
}
// Sum across the 16 lanes of a DPP row via row_ror 8/4/2/1 (VALU pipe).
static __device__ __forceinline__ float rsum16(float x) {
    x += __builtin_bit_cast(float, __builtin_amdgcn_update_dpp(
             0, __builtin_bit_cast(int, x), 0x128, 0xf, 0xf, false));
    x += __builtin_bit_cast(float, __builtin_amdgcn_update_dpp(
             0, __builtin_bit_cast(int, x), 0x124, 0xf, 0xf, false));
    x += __builtin_bit_cast(float, __builtin_amdgcn_update_dpp(
             0, __builtin_bit_cast(int, x), 0x122, 0xf, 0xf, false));
    x += __builtin_bit_cast(float, __builtin_amdgcn_update_dpp(
             0, __builtin_bit_cast(int, x), 0x121, 0xf, 0xf, false));
    return x;
}

// ---------------------------------------------------------------------------
__global__ __launch_bounds__(1024) void scan_counts(const int* __restrict__ counts,
                                                    int* __restrict__ offsets) {
    __shared__ int a[2048];
    const int t = threadIdx.x;
    a[t]        = (t        < BSEG) ? counts[t]        : 0;
    a[t + 1024] = (t + 1024 < BSEG) ? counts[t + 1024] : 0;
    for (int s = 1; s < 2048; s <<= 1) {
        __syncthreads();
        int x1 = (t >= s) ? a[t - s] : 0;
        int x2 = a[t + 1024 - s];
        __syncthreads();
        a[t] += x1;
        a[t + 1024] += x2;
    }
    __syncthreads();
    if (t == 0) offsets[0] = 0;
    offsets[t + 1] = a[t];
    if (t + 1024 < BSEG) offsets[t + 1025] = a[t + 1024];
}

__global__ __launch_bounds__(256) void fill_seg(const int* __restrict__ offsets,
                                                unsigned short* __restrict__ seg) {
    const int b  = blockIdx.x;
    const int lo = offsets[b], hi = offsets[b + 1];
    for (int i = lo + threadIdx.x; i < hi; i += 256) seg[i] = (unsigned short)b;
}

// W1T [256][32] (K zero-padded 16->32), W2T [256][256]; [n][k]-major bf16.
__global__ __launch_bounds__(256) void prep_weights(const float* __restrict__ W1,
                                                    const float* __restrict__ W2,
                                                    unsigned short* __restrict__ w1t,
                                                    unsigned short* __restrict__ w2t) {
    const int i = blockIdx.x * 256 + threadIdx.x;
    if (i < HDIM * 32) {
        int n = i >> 5, k = i & 31;
        w1t[i] = (k < DIN) ? f2bf(W1[k * HDIM + n]) : (unsigned short)0;
    } else {
        int j = i - HDIM * 32;
        if (j < HDIM * HDIM) {
            int n = j >> 8, k = j & 255;
            w2t[j] = f2bf(W2[k * HDIM + n]);
        }
    }
}

// ---------------------------------------------------------------------------
// Transposed-dataflow fused kernel: A = weights (m = H), B = points (n).
// 512 thr / 8 waves; wave w owns H-slice [w*32, w*32+32); tile = 64 points.
// D layout: lane l15 = point (col), quad*4+r = H row  ->  per-point LN is
// in-register + ds_add_f32 cross-wave; NO part machinery, NO D->A row
// exchange for LN.  h1 crosses LDS once (b64 writes / b128 reads).
// Chunked persistent tiles: pooled sums accumulate in registers across
// consecutive tiles, flushed (rsum16 + global atomic) on segment change.
// ---------------------------------------------------------------------------
__global__ __launch_bounds__(512, 4) void fused_phi_pool(
    const float* __restrict__ z,
    const unsigned short* __restrict__ w1t,
    const unsigned short* __restrict__ w2t,
    const float* __restrict__ b1, const float* __restrict__ g1, const float* __restrict__ be1,
    const float* __restrict__ b2, const float* __restrict__ g2, const float* __restrict__ be2,
    const unsigned short* __restrict__ seg,
    float* __restrict__ sums_h) {
    __shared__ __align__(16) unsigned short h1[MT][264];  // 33.8 KB (pad: +4 words)
    __shared__ __align__(16) float z_lds[2][MT][16];      // 8 KB, DMA double-buffer
    __shared__ __align__(16) float stats[2][MT][4];       // [p][pt][sL1,qL1,sL2,qL2]
    __shared__ __align__(16) float blds[6][HDIM];         // b1,g1,be1,b2,g2,be2

    const int tid  = threadIdx.x;
    const int wave = tid >> 6;
    const int lane = tid & 63;
    const int l15  = lane & 15;
    const int quad = lane >> 4;
    const bool zl  = (quad < 2);          // layer-1 B lanes with real k (<16)
    const int t0   = blockIdx.x * TPW;
    const int ntl  = (NTILE - t0 < TPW) ? (NTILE - t0) : TPW;   // may be <= 0

    // ---- stage biases/gamma/beta to LDS (saves ~40 VGPRs of per-H scalars)
    {
        const float* s6[6] = {b1, g1, be1, b2, g2, be2};
        for (int i = tid; i < 6 * HDIM; i += 512) blds[i >> 8][i & 255] = s6[i >> 8][i & 255];
    }
    if (tid < 128) ((f32x4*)stats)[tid] = f32x4{0.f, 0.f, 0.f, 0.f};

    // ---- W2 as A-operand, register-resident: A[m=Hout][k=Hin]
    bf16x8 bw2[2][8];
#pragma unroll
    for (int mt = 0; mt < 2; ++mt)
#pragma unroll
        for (int ks = 0; ks < 8; ++ks) {
            bw2[mt][ks] = ldb8(w2t + ((wave * 2 + mt) * 16 + l15) * 256 + ks * 32 + quad * 8);
            keep(bw2[mt][ks]);
        }

    // ---- prologue: DMA z for first tile (4 KB = 4 instrs, wave 0)
    if (ntl > 0 && wave == 0) {
        const float* gp = z + (size_t)t0 * (MT * 16) + lane * 4;
#pragma unroll
        for (int c = 0; c < 4; ++c) async16(gp + c * 256, &z_lds[0][c * 16][0]);
    }
    asm volatile("s_waitcnt vmcnt(0)");
    __syncthreads();

    float accp[2][4] = {};   // pooled partials (this wave's 8 H-values), lane-local
    int   cur = -1;

    for (int i = 0; i < ntl; ++i) {
        const int tile = t0 + i;
        const int p    = i & 1;
        // prefetch next tile's z (drained by the compiler's vmcnt(0) at B1)
        if (wave == 0 && i + 1 < ntl) {
            const float* gp = z + (size_t)(tile + 1) * (MT * 16) + lane * 4;
#pragma unroll
            for (int c = 0; c < 4; ++c) async16(gp + c * 256, &z_lds[p ^ 1][c * 16][0]);
        }

        // ---------------- layer 1: D1[H(w-slice)][pt] ----------------
        f32x4 acc1[2][4];
        {
            bf16x8 aw1[2];
#pragma unroll
            for (int mt = 0; mt < 2; ++mt)
                aw1[mt] = ldb8(w1t + ((wave * 2 + mt) * 16 + l15) * 32 + quad * 8);
#pragma unroll
            for (int nt = 0; nt < 4; ++nt) {
                bf16x8 bz;
                if (zl) {
                    f32x4 v0 = *(const f32x4*)&z_lds[p][nt * 16 + l15][quad * 8];
                    f32x4 v1 = *(const f32x4*)&z_lds[p][nt * 16 + l15][quad * 8 + 4];
                    us16x8 u;
                    u[0] = f2bf(v0[0]); u[1] = f2bf(v0[1]); u[2] = f2bf(v0[2]); u[3] = f2bf(v0[3]);
                    u[4] = f2bf(v1[0]); u[5] = f2bf(v1[1]); u[6] = f2bf(v1[2]); u[7] = f2bf(v1[3]);
                    bz = __builtin_bit_cast(bf16x8, u);
                } else {
                    us16x8 u = {0, 0, 0, 0, 0, 0, 0, 0};
                    bz = __builtin_bit_cast(bf16x8, u);
                }
                const f32x4 zero = {0.f, 0.f, 0.f, 0.f};
#pragma unroll
                for (int mt = 0; mt < 2; ++mt) acc1[mt][nt] = mfma16(aw1[mt], bz, zero);
            }
        }
        // bias + per-point LN partials (in-register over this wave's 8 H)
        {
            float4 bb[2];
#pragma unroll
            for (int mt = 0; mt < 2; ++mt)
                bb[mt] = *(const float4*)&blds[0][(wave * 2 + mt) * 16 + quad * 4];
#pragma unroll
            for (int nt = 0; nt < 4; ++nt) {
                float s = 0.f, q = 0.f;
#pragma unroll
                for (int mt = 0; mt < 2; ++mt)
#pragma unroll
                    for (int r = 0; r < 4; ++r) {
                        float y = acc1[mt][nt][r] + (&bb[mt].x)[r];
                        acc1[mt][nt][r] = y;
                        s += y; q += y * y;
                    }
                atomicAdd(&stats[p][nt * 16 + l15][0], s);
                atomicAdd(&stats[p][nt * 16 + l15][1], q);
            }
        }
        __syncthreads();   // B1: stats complete; z prefetch drained
        if (wave == 1) ((f32x4*)stats[p ^ 1])[lane] = f32x4{0.f, 0.f, 0.f, 0.f};
        // normalize + relu -> bf16 h1[pt][H]
        {
            float4 gg[2], ee[2];
#pragma unroll
            for (int mt = 0; mt < 2; ++mt) {
                gg[mt] = *(const float4*)&blds[1][(wave * 2 + mt) * 16 + quad * 4];
                ee[mt] = *(const float4*)&blds[2][(wave * 2 + mt) * 16 + quad * 4];
            }
#pragma unroll
            for (int nt = 0; nt < 4; ++nt) {
                float2 sq = *(const float2*)&stats[p][nt * 16 + l15][0];
                float mean = sq.x * (1.f / 256.f);
                float rs   = rsqrtf(fmaxf(sq.y * (1.f / 256.f) - mean * mean, 0.f) + 1e-5f);
#pragma unroll
                for (int mt = 0; mt < 2; ++mt) {
                    unsigned pk[2];
#pragma unroll
                    for (int h = 0; h < 2; ++h) {
                        float A0 = rs * (&gg[mt].x)[h * 2];
                        float A1 = rs * (&gg[mt].x)[h * 2 + 1];
                        float y0 = fmaxf(fmaf(acc1[mt][nt][h * 2],     A0,
                                              fmaf(-mean, A0, (&ee[mt].x)[h * 2])),     0.f);
                        float y1 = fmaxf(fmaf(acc1[mt][nt][h * 2 + 1], A1,
                                              fmaf(-mean, A1, (&ee[mt].x)[h * 2 + 1])), 0.f);
                        pk[h] = (unsigned)f2bf(y0) | ((unsigned)f2bf(y1) << 16);
                    }
                    *(uint2*)&h1[nt * 16 + l15][(wave * 2 + mt) * 16 + quad * 4] =
                        make_uint2(pk[0], pk[1]);
                }
            }
        }
        __syncthreads();   // B2: h1 ready

        // ---------------- layer 2: D2[Hout(w-slice)][pt] ----------------
        f32x4 acc2[2][4];
#pragma unroll
        for (int mt = 0; mt < 2; ++mt)
#pragma unroll
            for (int nt = 0; nt < 4; ++nt) acc2[mt][nt] = f32x4{0.f, 0.f, 0.f, 0.f};
#pragma unroll
        for (int ks = 0; ks < 8; ++ks) {
            bf16x8 hb[4];
#pragma unroll
            for (int nt = 0; nt < 4; ++nt)
                hb[nt] = ldb8(&h1[nt * 16 + l15][ks * 32 + quad * 8]);
#pragma unroll
            for (int mt = 0; mt < 2; ++mt)
#pragma unroll
                for (int nt = 0; nt < 4; ++nt)
                    acc2[mt][nt] = mfma16(bw2[mt][ks], hb[nt], acc2[mt][nt]);
        }
        // bias + per-point LN partials (slots 2,3)
        {
            float4 bb[2];
#pragma unroll
            for (int mt = 0; mt < 2; ++mt)
                bb[mt] = *(const float4*)&blds[3][(wave * 2 + mt) * 16 + quad * 4];
#pragma unroll
            for (int nt = 0; nt < 4; ++nt) {
                float s = 0.f, q = 0.f;
#pragma unroll
                for (int mt = 0; mt < 2; ++mt)
#pragma unroll
                    for (int r = 0; r < 4; ++r) {
                        float y = acc2[mt][nt][r] + (&bb[mt].x)[r];
                        acc2[mt][nt][r] = y;
                        s += y; q += y * y;
                    }
                atomicAdd(&stats[p][nt * 16 + l15][2], s);
                atomicAdd(&stats[p][nt * 16 + l15][3], q);
            }
        }
        __syncthreads();   // B3: layer-2 stats complete
        // normalize + relu in registers (h2 never hits LDS)
        {
            float4 gg[2], ee[2];
#pragma unroll
            for (int mt = 0; mt < 2; ++mt) {
                gg[mt] = *(const float4*)&blds[4][(wave * 2 + mt) * 16 + quad * 4];
                ee[mt] = *(const float4*)&blds[5][(wave * 2 + mt) * 16 + quad * 4];
            }
#pragma unroll
            for (int nt = 0; nt < 4; ++nt) {
                float2 sq = *(const float2*)&stats[p][nt * 16 + l15][2];
                float mean = sq.x * (1.f / 256.f);
                float rs   = rsqrtf(fmaxf(sq.y * (1.f / 256.f) - mean * mean, 0.f) + 1e-5f);
#pragma unroll
                for (int mt = 0; mt < 2; ++mt)
#pragma unroll
                    for (int r = 0; r < 4; ++r) {
                        float A = rs * (&gg[mt].x)[r];
                        acc2[mt][nt][r] =
                            fmaxf(fmaf(acc2[mt][nt][r], A, fmaf(-mean, A, (&ee[mt].x)[r])), 0.f);
                    }
            }
        }

        // ---------------- ragged pool: accumulate, flush on seg change ----
        const int s0   = (int)seg[tile * MT];
        const int s63  = (int)seg[tile * MT + MT - 1];
        if (cur != s0) {
            if (cur >= 0) {
#pragma unroll
                for (int mt = 0; mt < 2; ++mt)
#pragma unroll
                    for (int r = 0; r < 4; ++r) {
                        float v = rsum16(accp[mt][r]);
                        if (l15 == 0)
                            atomicAdd(&sums_h[cur * HDIM + (wave * 2 + mt) * 16 + quad * 4 + r], v);
                        accp[mt][r] = 0.f;
                    }
            }
            cur = s0;
        }
        if (s0 == s63) {   // tile inside one segment (~87% of tiles)
#pragma unroll
            for (int mt = 0; mt < 2; ++mt)
#pragma unroll
                for (int r = 0; r < 4; ++r)
                    accp[mt][r] += acc2[mt][0][r] + acc2[mt][1][r] + acc2[mt][2][r] + acc2[mt][3][r];
        } else {           // exactly 2 segments (min count 100 > 64)
            float pm[4];
#pragma unroll
            for (int nt = 0; nt < 4; ++nt)
                pm[nt] = ((int)seg[tile * MT + nt * 16 + l15] == s0) ? 1.f : 0.f;
            float vb[2][4];
#pragma unroll
            for (int mt = 0; mt < 2; ++mt)
#pragma unroll
                for (int r = 0; r < 4; ++r) {
                    float tot = acc2[mt][0][r] + acc2[mt][1][r] + acc2[mt][2][r] + acc2[mt][3][r];
                    float va  = 0.f;
#pragma unroll
                    for (int nt = 0; nt < 4; ++nt) va = fmaf(acc2[mt][nt][r], pm[nt], va);
                    accp[mt][r] += va;
                    vb[mt][r] = tot - va;
                }
            // flush s0 portion, switch to s63
#pragma unroll
            for (int mt = 0; mt < 2; ++mt)
#pragma unroll
                for (int r = 0; r < 4; ++r) {
                    float v = rsum16(accp[mt][r]);
                    if (l15 == 0)
                        atomicAdd(&sums_h[cur * HDIM + (wave * 2 + mt) * 16 + quad * 4 + r], v);
                    accp[mt][r] = vb[mt][r];
                }
            cur = s63;
        }
    }
    if (cur >= 0) {
#pragma unroll
        for (int mt = 0; mt < 2; ++mt)
#pragma unroll
            for (int r = 0; r < 4; ++r) {
                float v = rsum16(accp[mt][r]);
                if (l15 == 0)
                    atomicAdd(&sums_h[cur * HDIM + (wave * 2 + mt) * 16 + quad * 4 + r], v);
            }
    }
}

// ---------------------------------------------------------------------------
// emb[b] = (sums_h[b] @ W3) / count_b + b3
// ---------------------------------------------------------------------------
__global__ __launch_bounds__(256) void emb_gemm(const float* __restrict__ sums_h,
                                                const float* __restrict__ W3,
                                                const float* __restrict__ b3,
                                                const int* __restrict__ counts,
                                                float* __restrict__ emb) {
    const int b = blockIdx.x * 2 + (threadIdx.x >> 7);
    const int o = threadIdx.x & 127;
    const float* sh = sums_h + b * HDIM;
    float acc = 0.f;
#pragma unroll 8
    for (int k = 0; k < HDIM; ++k) acc = fmaf(sh[k], W3[k * DOUT + o], acc);
    emb[b * DOUT + o] = acc / (float)counts[b] + b3[o];
}

// ---------------------------------------------------------------------------
// out[n] = emb[seg[n]] ; 32 B/thread, plain coalesced stores (NT reverted)
// ---------------------------------------------------------------------------
__global__ __launch_bounds__(256) void broadcast_out(const float* __restrict__ emb,
                                                     const unsigned short* __restrict__ seg,
                                                     float* __restrict__ out) {
    const int idx = blockIdx.x * 256 + threadIdx.x;   // n*16 + oct, exactly N*16
    const int n = idx >> 4, oct = idx & 15;
    const int s = seg[n];
    const f32x4* ev = (const f32x4*)emb;
    f32x4 v0 = ev[s * 32 + oct * 2];
    f32x4 v1 = ev[s * 32 + oct * 2 + 1];
    ((f32x4*)out)[idx * 2]     = v0;
    ((f32x4*)out)[idx * 2 + 1] = v1;
}

// ---------------------------------------------------------------------------
extern "C" void kernel_launch(void* const* d_in, const int* in_sizes, int n_in,
                              void* d_out, int out_size, void* d_ws, size_t ws_size,
                              hipStream_t stream) {
    const float* z   = (const float*)d_in[0];
    const float* W1  = (const float*)d_in[1];
    const float* b1  = (const float*)d_in[2];
    const float* g1  = (const float*)d_in[3];
    const float* be1 = (const float*)d_in[4];
    const float* W2  = (const float*)d_in[5];
    const float* b2  = (const float*)d_in[6];
    const float* g2  = (const float*)d_in[7];
    const float* be2 = (const float*)d_in[8];
    const float* W3  = (const float*)d_in[9];
    const float* b3  = (const float*)d_in[10];
    const int* counts = (const int*)d_in[11];
    float* out = (float*)d_out;

    char* ws = (char*)d_ws;
    float*          sums_h  = (float*)(ws);                     // 2,048,000 B
    float*          emb     = (float*)(ws + 2048000);           // 1,024,000 B
    int*            offsets = (int*)  (ws + 3072000);           //     8,016 B
    unsigned short* seg     = (unsigned short*)(ws + 3080016);  // 2,000,000 B
    unsigned short* w1t     = (unsigned short*)(ws + 5080016);  //    16,384 B
    unsigned short* w2t     = (unsigned short*)(ws + 5096400);  //   131,072 B

    hipMemsetAsync(sums_h, 0, (size_t)BSEG * HDIM * sizeof(float), stream);
    scan_counts<<<1, 1024, 0, stream>>>(counts, offsets);
    fill_seg<<<BSEG, 256, 0, stream>>>(offsets, seg);
    prep_weights<<<(HDIM * 32 + HDIM * HDIM) / 256, 256, 0, stream>>>(W1, W2, w1t, w2t);
    fused_phi_pool<<<NWG, 512, 0, stream>>>(z, w1t, w2t,
                                            b1, g1, be1, b2, g2, be2,
                                            seg, sums_h);
    emb_gemm<<<BSEG / 2, 256, 0, stream>>>(sums_h, W3, b3, counts, emb);
    broadcast_out<<<NPTS * 16 / 256, 256, 0, stream>>>(emb, seg, out);
}